// Round 2
// baseline (71.876 us; speedup 1.0000x reference)
//
#include <hip/hip_runtime.h>

// Slater pairwise energy sum on MI355X.
// pairs/atom_types/cutoff are int32 on device (harness contract: integer -> const int*).
// Hot loop: stream pairs as int4 (2 pairs / 16B per lane), gather packed
// float4{x,y,z,bits(type)} per endpoint (L2-resident, 1.6 MB), one float2 A/B
// table lookup, fp32 accumulate -> wave shuffle reduce -> 1 atomic per block.

#ifndef SLATER_T
#define SLATER_T 16   // number of atom types (A,B are T x T)
#endif

__global__ __launch_bounds__(256)
void repack_kernel(const float* __restrict__ coords,
                   const int* __restrict__ types,
                   const float* __restrict__ A,
                   const float* __restrict__ B,
                   float4* __restrict__ packed,
                   float2* __restrict__ abt,
                   float* __restrict__ out, int out_size,
                   int n)
{
    int i = blockIdx.x * blockDim.x + threadIdx.x;
    if (i < out_size) out[i] = 0.0f;               // zero the output (harness poisons it)
    if (i < SLATER_T * SLATER_T) abt[i] = make_float2(A[i], B[i]);
    int stride = gridDim.x * blockDim.x;
    for (; i < n; i += stride) {
        float4 v;
        v.x = coords[3 * i + 0];
        v.y = coords[3 * i + 1];
        v.z = coords[3 * i + 2];
        v.w = __int_as_float(types[i]);
        packed[i] = v;
    }
}

__global__ __launch_bounds__(256)
void zero_kernel(float* __restrict__ out, int out_size)
{
    int i = blockIdx.x * blockDim.x + threadIdx.x;
    if (i < out_size) out[i] = 0.0f;
}

template <bool PACKED>
__global__ __launch_bounds__(256)
void slater_kernel(const int* __restrict__ pairs,
                   const float4* __restrict__ packed,
                   const float2* __restrict__ abt,
                   const float* __restrict__ coords,
                   const int* __restrict__ types,
                   const float* __restrict__ A,
                   const float* __restrict__ B,
                   const float* __restrict__ box,
                   const int* __restrict__ cutoffp,
                   float* __restrict__ out,
                   int nP)
{
    // ---- per-thread setup (uniform scalars; L1/K$ hits) ----
    float b00 = box[0], b01 = box[1], b02 = box[2];
    float b10 = box[3], b11 = box[4], b12 = box[5];
    float b20 = box[6], b21 = box[7], b22 = box[8];

    float C00 =  (b11 * b22 - b12 * b21);
    float C01 = -(b10 * b22 - b12 * b20);
    float C02 =  (b10 * b21 - b11 * b20);
    float C10 = -(b01 * b22 - b02 * b21);
    float C11 =  (b00 * b22 - b02 * b20);
    float C12 = -(b00 * b21 - b01 * b20);
    float C20 =  (b01 * b12 - b02 * b11);
    float C21 = -(b00 * b12 - b02 * b10);
    float C22 =  (b00 * b11 - b01 * b10);
    float det = b00 * C00 + b01 * C01 + b02 * C02;
    float inv_det = 1.0f / det;
    float i00 = C00 * inv_det, i01 = C10 * inv_det, i02 = C20 * inv_det;
    float i10 = C01 * inv_det, i11 = C11 * inv_det, i12 = C21 * inv_det;
    float i20 = C02 * inv_det, i21 = C12 * inv_det, i22 = C22 * inv_det;

    float cut = (float)(*cutoffp);

    float acc = 0.0f;
    int tid    = blockIdx.x * blockDim.x + threadIdx.x;
    int stride = gridDim.x * blockDim.x;

    auto body = [&](int ia, int ja) {
        float ax, ay, az, bx, by, bz;
        int ti, tj;
        if (PACKED) {
            float4 ca = packed[ia];           // one aligned 16B gather
            float4 cb = packed[ja];
            ax = ca.x; ay = ca.y; az = ca.z; ti = __float_as_int(ca.w);
            bx = cb.x; by = cb.y; bz = cb.z; tj = __float_as_int(cb.w);
        } else {
            ax = coords[3 * ia + 0]; ay = coords[3 * ia + 1]; az = coords[3 * ia + 2];
            bx = coords[3 * ja + 0]; by = coords[3 * ja + 1]; bz = coords[3 * ja + 2];
            ti = types[ia];
            tj = types[ja];
        }

        float dx = bx - ax, dy = by - ay, dz = bz - az;

        // s = dr @ inv_box; minimum image (jnp.round == round-half-even == rintf)
        float s0 = dx * i00 + dy * i10 + dz * i20;
        float s1 = dx * i01 + dy * i11 + dz * i21;
        float s2 = dx * i02 + dy * i12 + dz * i22;
        s0 -= rintf(s0);
        s1 -= rintf(s1);
        s2 -= rintf(s2);
        float d0 = s0 * b00 + s1 * b10 + s2 * b20;
        float d1 = s0 * b01 + s1 * b11 + s2 * b21;
        float d2 = s0 * b02 + s1 * b12 + s2 * b22;

        float r = sqrtf(d0 * d0 + d1 * d1 + d2 * d2);

        float Aij, Bij;
        if (PACKED) {
            float2 abv = abt[ti * SLATER_T + tj];
            Aij = abv.x; Bij = abv.y;
        } else {
            Aij = A[ti * SLATER_T + tj];
            Bij = B[ti * SLATER_T + tj];
        }

        float x  = Bij * r;
        float pf = x * x * (1.0f / 3.0f) + x + 1.0f;
        float e  = Aij * pf * __expf(-x);
        acc += (r <= cut) ? e : 0.0f;
    };

    // main loop: one int4 = two pairs per iteration (16B/lane coalesced)
    const int4* p4 = (const int4*)pairs;
    int n4 = nP >> 1;
    for (int p = tid; p < n4; p += stride) {
        int4 pr = p4[p];
        body(pr.x, pr.y);
        body(pr.z, pr.w);
    }
    // odd tail (at most one pair)
    if (tid == 0 && (nP & 1)) {
        body(pairs[2 * (nP - 1)], pairs[2 * (nP - 1) + 1]);
    }

    // ---- reduction: wave shuffle -> LDS -> one atomic per block ----
    #pragma unroll
    for (int off = 32; off > 0; off >>= 1)
        acc += __shfl_down(acc, off, 64);

    __shared__ float wsum[4];                 // 256 threads / 64 lanes
    int lane = threadIdx.x & 63;
    int wid  = threadIdx.x >> 6;
    if (lane == 0) wsum[wid] = acc;
    __syncthreads();
    if (threadIdx.x == 0) {
        float s = wsum[0] + wsum[1] + wsum[2] + wsum[3];
        atomicAdd(out, s);
    }
}

extern "C" void kernel_launch(void* const* d_in, const int* in_sizes, int n_in,
                              void* d_out, int out_size, void* d_ws, size_t ws_size,
                              hipStream_t stream)
{
    const float* coords = (const float*)d_in[0];
    const int*   pairs  = (const int*)d_in[1];   // int32 on device
    const float* box    = (const float*)d_in[2];
    const float* A      = (const float*)d_in[3];
    const float* B      = (const float*)d_in[4];
    const int*   cutoff = (const int*)d_in[5];
    const int*   types  = (const int*)d_in[6];   // int32 on device

    int n  = in_sizes[0] / 3;   // N atoms
    int nP = in_sizes[1] / 2;   // P pairs

    float* out = (float*)d_out;

    size_t packed_bytes = (size_t)n * sizeof(float4);
    size_t need = packed_bytes + (size_t)(SLATER_T * SLATER_T) * sizeof(float2);

    const int THREADS = 256;
    const int BLOCKS  = 2048;   // 256 CU x 8 blocks; grid-stride covers P

    if (ws_size >= need) {
        float4* packed = (float4*)d_ws;
        float2* abt    = (float2*)((char*)d_ws + packed_bytes);
        int rblocks = (n + THREADS - 1) / THREADS;
        if (rblocks > 2048) rblocks = 2048;
        repack_kernel<<<rblocks, THREADS, 0, stream>>>(coords, types, A, B, packed, abt,
                                                       out, out_size, n);
        slater_kernel<true><<<BLOCKS, THREADS, 0, stream>>>(
            pairs, packed, abt,
            nullptr, nullptr, nullptr, nullptr,
            box, cutoff, out, nP);
    } else {
        zero_kernel<<<(out_size + THREADS - 1) / THREADS, THREADS, 0, stream>>>(out, out_size);
        slater_kernel<false><<<BLOCKS, THREADS, 0, stream>>>(
            pairs, nullptr, nullptr,
            coords, types, A, B,
            box, cutoff, out, nP);
    }
}